// Round 15
// baseline (70.757 us; speedup 1.0000x reference)
//
#include <hip/hip_runtime.h>
#include <math.h>

#define NN 32
#define CC 512
#define PP 1024   // H*W
#define KK 64
static constexpr float EPS = 1e-12f;

typedef __attribute__((ext_vector_type(8))) short bf16x8;
typedef __attribute__((ext_vector_type(4))) float f32x4;
typedef __attribute__((ext_vector_type(4))) unsigned int u32x4;
union FragU { u32x4 u; bf16x8 h; };

// pack two fp32 into one u32 of 2 bf16 (RNE)
__device__ __forceinline__ unsigned int bfpair(float lo, float hi) {
    unsigned int ul = __builtin_bit_cast(unsigned int, lo);
    unsigned int uh = __builtin_bit_cast(unsigned int, hi);
    ul = ul + 0x7FFFu + ((ul >> 16) & 1u);
    uh = uh + 0x7FFFu + ((uh >> 16) & 1u);
    return (ul >> 16) | (uh & 0xFFFF0000u);
}

// ---------------- fused pixnorm + logits(MFMA) + softmax -> sab=(sa*iv) bf16, Spart ----------------
// grid: 256 blocks = n(32) x 128-px tile(8). 512 threads = 8 waves. (R13 verbatim)
__global__ void __launch_bounds__(512, 2) k_logits(
        const float* __restrict__ x, const float* __restrict__ w,
        const float* __restrict__ bias, unsigned int* __restrict__ sab,
        float* __restrict__ Spart) {
    int b = blockIdx.x;
    int n = b >> 3;
    int p0 = (b & 7) << 7;           // 128-px tile base
    int tid = threadIdx.x;
    int lane = tid & 63;
    int wv = __builtin_amdgcn_readfirstlane(tid >> 6);   // 0..7 = px tile
    int l15 = lane & 15, l4 = lane >> 4;
    int rp = tid >> 4;               // staging cpair row 0..31
    int px8 = (tid & 15) << 3;       // staging px octet

    __shared__ unsigned int smem_u[26240];   // 104960 B
    unsigned int* XP  = smem_u;              // 2 x [128][33] u32
    unsigned int* WBF = smem_u + 8448;       // [64][260] u32
    float* RED  = (float*)(smem_u + 25088);  // [8][128] ssq / S partials
    float* REDI = (float*)(smem_u + 26112);  // [128] inv per px

    // ---- stage whole W (fp32 -> bf16 pairs) into LDS once ----
    {
        int k = tid >> 3, cb = (tid & 7) << 5;   // cb in u32 pairs (32 pairs = 64 floats)
        const float* wsrc = w + (k << 9) + (cb << 1);
#pragma unroll
        for (int i = 0; i < 8; ++i) {
            float4 f0 = *(const float4*)&wsrc[(i << 3)];
            float4 f1 = *(const float4*)&wsrc[(i << 3) + 4];
            u32x4 v;
            v[0] = bfpair(f0.x, f0.y); v[1] = bfpair(f0.z, f0.w);
            v[2] = bfpair(f1.x, f1.y); v[3] = bfpair(f1.z, f1.w);
            *(u32x4*)&WBF[k * 260 + cb + (i << 2)] = v;
        }
    }

    const float* xb = x + (size_t)n * CC * PP + p0;

    f32x4 c0v = {0.f, 0.f, 0.f, 0.f};
    f32x4 c1v = {0.f, 0.f, 0.f, 0.f};
    f32x4 c2v = {0.f, 0.f, 0.f, 0.f};
    f32x4 c3v = {0.f, 0.f, 0.f, 0.f};
    float ssq[8] = {};
    float4 a0, a1, b0, b1;

#define PFL(i) { const float* xa = xb + (size_t)((i) * 64 + 2 * rp) * PP + px8; \
        a0 = *(const float4*)xa; a1 = *(const float4*)(xa + 4); \
        b0 = *(const float4*)(xa + PP); b1 = *(const float4*)(xa + PP + 4); }

#define MSTEP(H) { \
        FragU bfr; \
        int ob = xo + ((H) << 4); \
        bfr.u[0] = xq[ob]; bfr.u[1] = xq[ob + 1]; \
        bfr.u[2] = xq[ob + 2]; bfr.u[3] = xq[ob + 3]; \
        int oa = l15 * 260 + (i << 5) + ((H) << 4) + (l4 << 2); \
        FragU af; \
        af.u = *(const u32x4*)&WBF[oa]; \
        c0v = __builtin_amdgcn_mfma_f32_16x16x32_bf16(af.h, bfr.h, c0v, 0, 0, 0); \
        af.u = *(const u32x4*)&WBF[oa + 4160]; \
        c1v = __builtin_amdgcn_mfma_f32_16x16x32_bf16(af.h, bfr.h, c1v, 0, 0, 0); \
        af.u = *(const u32x4*)&WBF[oa + 8320]; \
        c2v = __builtin_amdgcn_mfma_f32_16x16x32_bf16(af.h, bfr.h, c2v, 0, 0, 0); \
        af.u = *(const u32x4*)&WBF[oa + 12480]; \
        c3v = __builtin_amdgcn_mfma_f32_16x16x32_bf16(af.h, bfr.h, c3v, 0, 0, 0); \
    }

    PFL(0);
#pragma unroll 1
    for (int i = 0; i < 8; ++i) {
        __syncthreads();   // buffer free + (i==0) WBF visible
        unsigned int* xp = XP + (i & 1) * 4224;
        float av[8] = {a0.x, a0.y, a0.z, a0.w, a1.x, a1.y, a1.z, a1.w};
        float bv[8] = {b0.x, b0.y, b0.z, b0.w, b1.x, b1.y, b1.z, b1.w};
#pragma unroll
        for (int j = 0; j < 8; ++j) {
            xp[(px8 + j) * 33 + rp] = bfpair(av[j], bv[j]);
            ssq[j] = fmaf(av[j], av[j], fmaf(bv[j], bv[j], ssq[j]));
        }
        if (i < 7) { PFL(i + 1); }
        __syncthreads();   // staged chunk visible
        const unsigned int* xq = XP + (i & 1) * 4224;
        int xo = (wv * 16 + l15) * 33 + (l4 << 2);
        MSTEP(0);
        MSTEP(1);
    }
#undef PFL
#undef MSTEP

    // ---- per-px ssq -> inv ----
#pragma unroll
    for (int j = 0; j < 8; ++j) {
        ssq[j] += __shfl_xor(ssq[j], 16);
        ssq[j] += __shfl_xor(ssq[j], 32);
    }
    if (l4 == 0) {
#pragma unroll
        for (int j = 0; j < 8; ++j) RED[(wv << 7) + px8 + j] = ssq[j];
    }
    __syncthreads();
    if (tid < 128) {
        float s = 0.f;
#pragma unroll
        for (int w8 = 0; w8 < 8; ++w8) s += RED[(w8 << 7) + tid];
        REDI[tid] = 1.0f / fmaxf(sqrtf(s), EPS);
    }
    __syncthreads();

    // ---- softmax over 64 k (in-lane 16 + shfl over l4) ----
    float inv = REDI[(wv << 4) + l15];
    float lg[16];
#pragma unroll
    for (int r = 0; r < 4; ++r) {
        lg[r]      = c0v[r];
        lg[4 + r]  = c1v[r];
        lg[8 + r]  = c2v[r];
        lg[12 + r] = c3v[r];
    }
    float m = -1e30f;
#pragma unroll
    for (int kk = 0; kk < 16; ++kk) {
        int k = ((kk >> 2) << 4) + (l4 << 2) + (kk & 3);
        lg[kk] = fmaf(lg[kk], inv, bias[k]);
        m = fmaxf(m, lg[kk]);
    }
    m = fmaxf(m, __shfl_xor(m, 16));
    m = fmaxf(m, __shfl_xor(m, 32));
    float sm = 0.f;
#pragma unroll
    for (int kk = 0; kk < 16; ++kk) {
        lg[kk] = __expf(lg[kk] - m);
        sm += lg[kk];
    }
    sm += __shfl_xor(sm, 16);
    sm += __shfl_xor(sm, 32);
    float si = 1.0f / sm;

    // ---- store sab = sa*iv (bf16 pairs) + S partials ----
    int pcol = p0 + (wv << 4) + l15;
#pragma unroll
    for (int kk = 0; kk < 16; ++kk) {
        int k = ((kk >> 2) << 4) + (l4 << 2) + (kk & 3);
        float v = lg[kk] * si;                 // sa
        float vs = v;
        vs += __shfl_xor(vs, 1);
        vs += __shfl_xor(vs, 2);
        vs += __shfl_xor(vs, 4);
        vs += __shfl_xor(vs, 8);               // sum over the wave's 16 px
        float vi = v * inv;                    // sa*iv
        float vh = __shfl_xor(vi, 1);
        if ((l15 & 1) == 0)
            sab[(((size_t)(n * KK + k) << 10) + pcol) >> 1] = bfpair(vi, vh);
        if (l15 == 0) RED[(wv << 6) + k] = vs;
    }
    __syncthreads();
    if (tid < 64) {
        float s = 0.f;
#pragma unroll
        for (int w8 = 0; w8 < 8; ++w8) s += RED[(w8 << 6) + tid];
        Spart[(((b & 7) * NN) + n) * KK + tid] = s;
    }
}

// ---------------- vpart[q][n][k][c] = sum_{p in quarter} (sa*iv)*x  (MFMA) ----------------
// grid: 1024 blocks, b = ct*128 + n*4 + q  (8 ct-blocks sharing sab land on one XCD).
// 512 threads = 8 waves. LDS-free; explicit depth-2 register prefetch.
__global__ void __launch_bounds__(512) k_vlad(
        const float* __restrict__ x, const unsigned int* __restrict__ sab,
        float* __restrict__ vpart) {
    int b = blockIdx.x;
    int ct = b >> 7;              // c tile 0..7
    int nb = (b >> 2) & 31;       // n
    int q  = b & 3;               // px quarter 0..3
    int c0 = ct << 6;
    int tid = threadIdx.x;
    int lane = tid & 63;
    int wv = __builtin_amdgcn_readfirstlane(tid >> 6);   // 0..7
    int l15 = lane & 15, l4 = lane >> 4;
    int kt = wv & 3;
    int ctb = (wv >> 2) << 1;     // 0 or 2

    // A: sab row (nb*64 + kt*16 + l15), u32 row stride 512; quarter q; px chunk l4*8
    const unsigned int* sap = sab + ((size_t)(nb * KK + kt * 16 + l15) << 9)
                              + (q << 7) + (l4 << 2);
    // B: x rows c = nb*512 + c0 + ctb*16 + l15 (acc0) and +16 (acc1)
    const float* xb0 = x + ((size_t)(nb * CC + c0 + ctb * 16 + l15) << 10)
                       + (q << 8) + (l4 << 3);
    const float* xb1 = xb0 + (16 << 10);

    f32x4 acc0 = {0.f, 0.f, 0.f, 0.f};
    f32x4 acc1 = {0.f, 0.f, 0.f, 0.f};

    u32x4 aA, aB;
    float4 fA0, fA1, gA0, gA1, fB0, fB1, gB0, gB1;

#define LOADA(i) { aA = *(const u32x4*)(sap + ((i) << 4)); \
        fA0 = *(const float4*)(xb0 + ((i) << 5)); \
        fA1 = *(const float4*)(xb0 + ((i) << 5) + 4); \
        gA0 = *(const float4*)(xb1 + ((i) << 5)); \
        gA1 = *(const float4*)(xb1 + ((i) << 5) + 4); }
#define LOADB(i) { aB = *(const u32x4*)(sap + ((i) << 4)); \
        fB0 = *(const float4*)(xb0 + ((i) << 5)); \
        fB1 = *(const float4*)(xb0 + ((i) << 5) + 4); \
        gB0 = *(const float4*)(xb1 + ((i) << 5)); \
        gB1 = *(const float4*)(xb1 + ((i) << 5) + 4); }

#define BODY(AR, F0, F1, G0, G1, LOADNEXT) { \
        LOADNEXT; \
        FragU af, bf0, bf1; \
        af.u = AR; \
        bf0.u[0] = bfpair(F0.x, F0.y); bf0.u[1] = bfpair(F0.z, F0.w); \
        bf0.u[2] = bfpair(F1.x, F1.y); bf0.u[3] = bfpair(F1.z, F1.w); \
        bf1.u[0] = bfpair(G0.x, G0.y); bf1.u[1] = bfpair(G0.z, G0.w); \
        bf1.u[2] = bfpair(G1.x, G1.y); bf1.u[3] = bfpair(G1.z, G1.w); \
        acc0 = __builtin_amdgcn_mfma_f32_16x16x32_bf16(af.h, bf0.h, acc0, 0, 0, 0); \
        acc1 = __builtin_amdgcn_mfma_f32_16x16x32_bf16(af.h, bf1.h, acc1, 0, 0, 0); \
    }

    LOADA(0); LOADB(1);
#pragma unroll 1
    for (int i = 0; i < 8; i += 2) {         // 8 k-steps x 32 px = 256 px (the quarter)
        if (i < 6) { BODY(aA, fA0, fA1, gA0, gA1, LOADA(i + 2)); }
        else       { BODY(aA, fA0, fA1, gA0, gA1, ); }
        if (i < 5) { BODY(aB, fB0, fB1, gB0, gB1, LOADB(i + 3)); }
        else       { BODY(aB, fB0, fB1, gB0, gB1, ); }
    }
#undef LOADA
#undef LOADB
#undef BODY

    // ---- epilogue: write raw partial accumulators ----
    float* vbase = vpart + (size_t)q * NN * KK * CC;
#pragma unroll
    for (int r = 0; r < 4; ++r) {
        int k = kt * 16 + (l4 << 2) + r;
        int cg = c0 + ctb * 16 + l15;
        float* vp = vbase + ((size_t)nb * KK + k) * CC + cg;
        vp[0]  = acc0[r];
        vp[16] = acc1[r];
    }
}

// ---------------- vlad = sum_q vpart[q] - S*cent; per-row sumsq + inv norm ----------------
__global__ void k_rownorm(const float* __restrict__ vpart, const float* __restrict__ Spart,
                          const float* __restrict__ cent, float* __restrict__ vlad,
                          float* __restrict__ rinv, float* __restrict__ rsq) {
    int r = blockIdx.x * 4 + (threadIdx.x >> 6);   // n*KK+k
    int lane = threadIdx.x & 63;
    int n = r >> 6, k = r & 63;
    float S = 0.f;
#pragma unroll
    for (int pt = 0; pt < 8; ++pt) S += Spart[(pt * NN + n) * KK + k];
    const float* a0 = vpart + (size_t)r * CC;
    const float* a1 = a0 + (size_t)NN * KK * CC;
    const float* a2 = a1 + (size_t)NN * KK * CC;
    const float* a3 = a2 + (size_t)NN * KK * CC;
    const float* cp = cent + (size_t)k * CC;
    float* vo = vlad + (size_t)r * CC;
    float s = 0.f;
#pragma unroll
    for (int i = 0; i < CC / 64; ++i) {
        int c = i * 64 + lane;
        float v = ((a0[c] + a1[c]) + (a2[c] + a3[c])) - S * cp[c];
        vo[c] = v;
        s = fmaf(v, v, s);
    }
#pragma unroll
    for (int off = 32; off > 0; off >>= 1) s += __shfl_xor(s, off);
    if (lane == 0) {
        float iv = 1.0f / fmaxf(sqrtf(s), EPS);
        rinv[r] = iv;
        rsq[r] = s * iv * iv;
    }
}

// ---------------- final scale (tinv computed in-block from rsq) ----------------
__global__ void k_final(const float* __restrict__ vlad, const float* __restrict__ rinv,
                        const float* __restrict__ rsq, float* __restrict__ out) {
    size_t i4 = (size_t)blockIdx.x * 256 + threadIdx.x;   // over 262144 float4s
    int row = (int)(i4 >> 7);
    int n = row >> 6;
    int lane = threadIdx.x & 63;
    float s = rsq[(n << 6) + lane];
#pragma unroll
    for (int off = 32; off > 0; off >>= 1) s += __shfl_xor(s, off);
    float tinv = 1.0f / fmaxf(sqrtf(s), EPS);
    float4 v = ((const float4*)vlad)[i4];
    float sc = rinv[row] * tinv;
    float4 o{v.x * sc, v.y * sc, v.z * sc, v.w * sc};
    ((float4*)out)[i4] = o;
}

extern "C" void kernel_launch(void* const* d_in, const int* in_sizes, int n_in,
                              void* d_out, int out_size, void* d_ws, size_t ws_size,
                              hipStream_t stream) {
    const float* x    = (const float*)d_in[0];
    const float* w    = (const float*)d_in[1];
    const float* bias = (const float*)d_in[2];
    const float* cent = (const float*)d_in[3];
    float* ws = (float*)d_ws;

    float* vlad  = ws;                                // 1048576
    float* vpart = vlad + (size_t)NN * KK * CC;       // 4194304 (four quarters)
    float* Spart = vpart + (size_t)4 * NN * KK * CC;  // 16384 (8 partials)
    float* rinv  = Spart + 8 * NN * KK;               // 2048
    float* rsq   = rinv + NN * KK;                    // 2048
    unsigned int* sab = (unsigned int*)(rsq + NN * KK);   // 1048576 u32 (sa*iv bf16 pairs)

    float* out = (float*)d_out;

    k_logits<<<dim3(256), dim3(512), 0, stream>>>(x, w, bias, sab, Spart);
    k_vlad<<<dim3(1024), dim3(512), 0, stream>>>(x, sab, vpart);
    k_rownorm<<<dim3(NN * KK / 4), dim3(256), 0, stream>>>(
        vpart, Spart, cent, vlad, rinv, rsq);
    k_final<<<dim3(1024), dim3(256), 0, stream>>>(vlad, rinv, rsq, out);
}

// Round 16
// 66.171 us; speedup vs baseline: 1.0693x; 1.0693x over previous
//
#include <hip/hip_runtime.h>
#include <math.h>

#define NN 32
#define CC 512
#define PP 1024   // H*W
#define KK 64
static constexpr float EPS = 1e-12f;

typedef __attribute__((ext_vector_type(8))) short bf16x8;
typedef __attribute__((ext_vector_type(4))) float f32x4;
typedef __attribute__((ext_vector_type(4))) unsigned int u32x4;
union FragU { u32x4 u; bf16x8 h; };

// pack two fp32 into one u32 of 2 bf16 (RNE)
__device__ __forceinline__ unsigned int bfpair(float lo, float hi) {
    unsigned int ul = __builtin_bit_cast(unsigned int, lo);
    unsigned int uh = __builtin_bit_cast(unsigned int, hi);
    ul = ul + 0x7FFFu + ((ul >> 16) & 1u);
    uh = uh + 0x7FFFu + ((uh >> 16) & 1u);
    return (ul >> 16) | (uh & 0xFFFF0000u);
}

// ---------------- fused pixnorm + logits(MFMA) + softmax -> sab=(sa*iv) bf16, Spart ----------------
// grid: 256 blocks = n(32) x 128-px tile(8). 512 threads = 8 waves. (R13 verbatim)
__global__ void __launch_bounds__(512, 2) k_logits(
        const float* __restrict__ x, const float* __restrict__ w,
        const float* __restrict__ bias, unsigned int* __restrict__ sab,
        float* __restrict__ Spart) {
    int b = blockIdx.x;
    int n = b >> 3;
    int p0 = (b & 7) << 7;           // 128-px tile base
    int tid = threadIdx.x;
    int lane = tid & 63;
    int wv = __builtin_amdgcn_readfirstlane(tid >> 6);   // 0..7 = px tile
    int l15 = lane & 15, l4 = lane >> 4;
    int rp = tid >> 4;               // staging cpair row 0..31
    int px8 = (tid & 15) << 3;       // staging px octet

    __shared__ unsigned int smem_u[26240];   // 104960 B
    unsigned int* XP  = smem_u;              // 2 x [128][33] u32
    unsigned int* WBF = smem_u + 8448;       // [64][260] u32
    float* RED  = (float*)(smem_u + 25088);  // [8][128] ssq / S partials
    float* REDI = (float*)(smem_u + 26112);  // [128] inv per px

    // ---- stage whole W (fp32 -> bf16 pairs) into LDS once ----
    {
        int k = tid >> 3, cb = (tid & 7) << 5;   // cb in u32 pairs (32 pairs = 64 floats)
        const float* wsrc = w + (k << 9) + (cb << 1);
#pragma unroll
        for (int i = 0; i < 8; ++i) {
            float4 f0 = *(const float4*)&wsrc[(i << 3)];
            float4 f1 = *(const float4*)&wsrc[(i << 3) + 4];
            u32x4 v;
            v[0] = bfpair(f0.x, f0.y); v[1] = bfpair(f0.z, f0.w);
            v[2] = bfpair(f1.x, f1.y); v[3] = bfpair(f1.z, f1.w);
            *(u32x4*)&WBF[k * 260 + cb + (i << 2)] = v;
        }
    }

    const float* xb = x + (size_t)n * CC * PP + p0;

    f32x4 c0v = {0.f, 0.f, 0.f, 0.f};
    f32x4 c1v = {0.f, 0.f, 0.f, 0.f};
    f32x4 c2v = {0.f, 0.f, 0.f, 0.f};
    f32x4 c3v = {0.f, 0.f, 0.f, 0.f};
    float ssq[8] = {};
    float4 a0, a1, b0, b1;

#define PFL(i) { const float* xa = xb + (size_t)((i) * 64 + 2 * rp) * PP + px8; \
        a0 = *(const float4*)xa; a1 = *(const float4*)(xa + 4); \
        b0 = *(const float4*)(xa + PP); b1 = *(const float4*)(xa + PP + 4); }

#define MSTEP(H) { \
        FragU bfr; \
        int ob = xo + ((H) << 4); \
        bfr.u[0] = xq[ob]; bfr.u[1] = xq[ob + 1]; \
        bfr.u[2] = xq[ob + 2]; bfr.u[3] = xq[ob + 3]; \
        int oa = l15 * 260 + (i << 5) + ((H) << 4) + (l4 << 2); \
        FragU af; \
        af.u = *(const u32x4*)&WBF[oa]; \
        c0v = __builtin_amdgcn_mfma_f32_16x16x32_bf16(af.h, bfr.h, c0v, 0, 0, 0); \
        af.u = *(const u32x4*)&WBF[oa + 4160]; \
        c1v = __builtin_amdgcn_mfma_f32_16x16x32_bf16(af.h, bfr.h, c1v, 0, 0, 0); \
        af.u = *(const u32x4*)&WBF[oa + 8320]; \
        c2v = __builtin_amdgcn_mfma_f32_16x16x32_bf16(af.h, bfr.h, c2v, 0, 0, 0); \
        af.u = *(const u32x4*)&WBF[oa + 12480]; \
        c3v = __builtin_amdgcn_mfma_f32_16x16x32_bf16(af.h, bfr.h, c3v, 0, 0, 0); \
    }

    PFL(0);
#pragma unroll 1
    for (int i = 0; i < 8; ++i) {
        __syncthreads();   // buffer free + (i==0) WBF visible
        unsigned int* xp = XP + (i & 1) * 4224;
        float av[8] = {a0.x, a0.y, a0.z, a0.w, a1.x, a1.y, a1.z, a1.w};
        float bv[8] = {b0.x, b0.y, b0.z, b0.w, b1.x, b1.y, b1.z, b1.w};
#pragma unroll
        for (int j = 0; j < 8; ++j) {
            xp[(px8 + j) * 33 + rp] = bfpair(av[j], bv[j]);
            ssq[j] = fmaf(av[j], av[j], fmaf(bv[j], bv[j], ssq[j]));
        }
        if (i < 7) { PFL(i + 1); }
        __syncthreads();   // staged chunk visible
        const unsigned int* xq = XP + (i & 1) * 4224;
        int xo = (wv * 16 + l15) * 33 + (l4 << 2);
        MSTEP(0);
        MSTEP(1);
    }
#undef PFL
#undef MSTEP

    // ---- per-px ssq -> inv ----
#pragma unroll
    for (int j = 0; j < 8; ++j) {
        ssq[j] += __shfl_xor(ssq[j], 16);
        ssq[j] += __shfl_xor(ssq[j], 32);
    }
    if (l4 == 0) {
#pragma unroll
        for (int j = 0; j < 8; ++j) RED[(wv << 7) + px8 + j] = ssq[j];
    }
    __syncthreads();
    if (tid < 128) {
        float s = 0.f;
#pragma unroll
        for (int w8 = 0; w8 < 8; ++w8) s += RED[(w8 << 7) + tid];
        REDI[tid] = 1.0f / fmaxf(sqrtf(s), EPS);
    }
    __syncthreads();

    // ---- softmax over 64 k (in-lane 16 + shfl over l4) ----
    float inv = REDI[(wv << 4) + l15];
    float lg[16];
#pragma unroll
    for (int r = 0; r < 4; ++r) {
        lg[r]      = c0v[r];
        lg[4 + r]  = c1v[r];
        lg[8 + r]  = c2v[r];
        lg[12 + r] = c3v[r];
    }
    float m = -1e30f;
#pragma unroll
    for (int kk = 0; kk < 16; ++kk) {
        int k = ((kk >> 2) << 4) + (l4 << 2) + (kk & 3);
        lg[kk] = fmaf(lg[kk], inv, bias[k]);
        m = fmaxf(m, lg[kk]);
    }
    m = fmaxf(m, __shfl_xor(m, 16));
    m = fmaxf(m, __shfl_xor(m, 32));
    float sm = 0.f;
#pragma unroll
    for (int kk = 0; kk < 16; ++kk) {
        lg[kk] = __expf(lg[kk] - m);
        sm += lg[kk];
    }
    sm += __shfl_xor(sm, 16);
    sm += __shfl_xor(sm, 32);
    float si = 1.0f / sm;

    // ---- store sab = sa*iv (bf16 pairs) + S partials ----
    int pcol = p0 + (wv << 4) + l15;
#pragma unroll
    for (int kk = 0; kk < 16; ++kk) {
        int k = ((kk >> 2) << 4) + (l4 << 2) + (kk & 3);
        float v = lg[kk] * si;                 // sa
        float vs = v;
        vs += __shfl_xor(vs, 1);
        vs += __shfl_xor(vs, 2);
        vs += __shfl_xor(vs, 4);
        vs += __shfl_xor(vs, 8);               // sum over the wave's 16 px
        float vi = v * inv;                    // sa*iv
        float vh = __shfl_xor(vi, 1);
        if ((l15 & 1) == 0)
            sab[(((size_t)(n * KK + k) << 10) + pcol) >> 1] = bfpair(vi, vh);
        if (l15 == 0) RED[(wv << 6) + k] = vs;
    }
    __syncthreads();
    if (tid < 64) {
        float s = 0.f;
#pragma unroll
        for (int w8 = 0; w8 < 8; ++w8) s += RED[(w8 << 6) + tid];
        Spart[(((b & 7) * NN) + n) * KK + tid] = s;
    }
}

// ---------------- vpart[half][n][k][c] = sum_{p in half} (sa*iv)*x  (MFMA) ----------------
// grid: 512 blocks = n(32) x p-half(2) x 64-c tile(8). 512 threads = 8 waves.
// Wide 128-px chunks (4/block): 96 B/lane prefetch in flight, 8 barriers total.
// LDS [2][64][66] u32 per operand (pad 66 -> bank step 2, <=2-way = free).
__global__ void __launch_bounds__(512, 2) k_vlad(
        const float* __restrict__ x, const unsigned int* __restrict__ sab,
        float* __restrict__ vpart) {
    int b = blockIdx.x;
    int nb = b >> 4;
    int half = (b >> 3) & 1;
    int c0 = (b & 7) << 6;
    int tid = threadIdx.x;
    int lane = tid & 63;
    int wv = __builtin_amdgcn_readfirstlane(tid >> 6);   // 0..7
    int l15 = lane & 15, l4 = lane >> 4;
    int kt = wv & 3;
    int ctb = (wv >> 2) << 1;      // 0 or 2

    __shared__ unsigned int smem_u[16896];   // 67584 B -> 2 blocks/CU
    unsigned int* SAB = smem_u;              // [2][64][66] sa*iv bf16 pairs
    unsigned int* XT  = smem_u + 8448;       // [2][64][66] x bf16 pairs

    int tr = tid >> 3;             // row 0..63 (k for sab, c for x)
    int tc = tid & 7;              // col group 0..7 (32 B each)

    // sab: row stride 512 u32; chunk i covers 64 u32 (128 px)
    const unsigned int* sap = sab + ((size_t)(nb * KK + tr) << 9) + (half << 8) + (tc << 3);
    // x: row stride 1024 f; chunk i covers 128 f
    const float* xbp = x + ((size_t)(nb * CC + c0 + tr) << 10) + (half << 9) + (tc << 4);

    f32x4 acc0 = {0.f, 0.f, 0.f, 0.f};
    f32x4 acc1 = {0.f, 0.f, 0.f, 0.f};

    u32x4 sA0, sA1, sB0, sB1;
    float4 xA0, xA1, xA2, xA3, xB0, xB1, xB2, xB3;

#define LOADA(i) { sA0 = *(const u32x4*)(sap + (i) * 64); \
        sA1 = *(const u32x4*)(sap + (i) * 64 + 4); \
        xA0 = *(const float4*)(xbp + (i) * 128); \
        xA1 = *(const float4*)(xbp + (i) * 128 + 4); \
        xA2 = *(const float4*)(xbp + (i) * 128 + 8); \
        xA3 = *(const float4*)(xbp + (i) * 128 + 12); }
#define LOADB(i) { sB0 = *(const u32x4*)(sap + (i) * 64); \
        sB1 = *(const u32x4*)(sap + (i) * 64 + 4); \
        xB0 = *(const float4*)(xbp + (i) * 128); \
        xB1 = *(const float4*)(xbp + (i) * 128 + 4); \
        xB2 = *(const float4*)(xbp + (i) * 128 + 8); \
        xB3 = *(const float4*)(xbp + (i) * 128 + 12); }

#define BODY(S0, S1, X0, X1, X2, X3, i, LOADNEXT) { \
        __syncthreads(); \
        int bo = ((i) & 1) * 4224; \
        unsigned int* sd = SAB + bo + tr * 66 + (tc << 3); \
        *(u32x4*)sd = S0; *(u32x4*)(sd + 4) = S1; \
        u32x4 xw0, xw1; \
        xw0[0] = bfpair(X0.x, X0.y); xw0[1] = bfpair(X0.z, X0.w); \
        xw0[2] = bfpair(X1.x, X1.y); xw0[3] = bfpair(X1.z, X1.w); \
        xw1[0] = bfpair(X2.x, X2.y); xw1[1] = bfpair(X2.z, X2.w); \
        xw1[2] = bfpair(X3.x, X3.y); xw1[3] = bfpair(X3.z, X3.w); \
        unsigned int* xd = XT + bo + tr * 66 + (tc << 3); \
        *(u32x4*)xd = xw0; *(u32x4*)(xd + 4) = xw1; \
        LOADNEXT; \
        __syncthreads(); \
        const unsigned int* sa_l = SAB + bo + (kt * 16 + l15) * 66 + (l4 << 2); \
        const unsigned int* xb_l = XT + bo + (ctb * 16 + l15) * 66 + (l4 << 2); \
        _Pragma("unroll") \
        for (int ks = 0; ks < 4; ++ks) { \
            FragU af, bf0, bf1; \
            af.u  = *(const u32x4*)(sa_l + ks * 16); \
            bf0.u = *(const u32x4*)(xb_l + ks * 16); \
            bf1.u = *(const u32x4*)(xb_l + 16 * 66 + ks * 16); \
            acc0 = __builtin_amdgcn_mfma_f32_16x16x32_bf16(af.h, bf0.h, acc0, 0, 0, 0); \
            acc1 = __builtin_amdgcn_mfma_f32_16x16x32_bf16(af.h, bf1.h, acc1, 0, 0, 0); \
        } \
    }

    LOADA(0); LOADB(1);
    BODY(sA0, sA1, xA0, xA1, xA2, xA3, 0, LOADA(2));
    BODY(sB0, sB1, xB0, xB1, xB2, xB3, 1, LOADB(3));
    BODY(sA0, sA1, xA0, xA1, xA2, xA3, 2, );
    BODY(sB0, sB1, xB0, xB1, xB2, xB3, 3, );
#undef LOADA
#undef LOADB
#undef BODY

    // ---- epilogue: write raw partial accumulators ----
    float* vbase = vpart + (size_t)half * NN * KK * CC;
#pragma unroll
    for (int r = 0; r < 4; ++r) {
        int k = kt * 16 + (l4 << 2) + r;
        int cg = c0 + ctb * 16 + l15;
        float* vp = vbase + ((size_t)nb * KK + k) * CC + cg;
        vp[0]  = acc0[r];
        vp[16] = acc1[r];
    }
}

// ---------------- vlad = vp0+vp1-S*cent; per-row sumsq + inv norm ----------------
__global__ void k_rownorm(const float* __restrict__ vp0, const float* __restrict__ vp1,
                          const float* __restrict__ Spart, const float* __restrict__ cent,
                          float* __restrict__ vlad, float* __restrict__ rinv,
                          float* __restrict__ rsq) {
    int r = blockIdx.x * 4 + (threadIdx.x >> 6);   // n*KK+k
    int lane = threadIdx.x & 63;
    int n = r >> 6, k = r & 63;
    float S = 0.f;
#pragma unroll
    for (int pt = 0; pt < 8; ++pt) S += Spart[(pt * NN + n) * KK + k];
    const float* a  = vp0 + (size_t)r * CC;
    const float* bq = vp1 + (size_t)r * CC;
    const float* cp = cent + (size_t)k * CC;
    float* vo = vlad + (size_t)r * CC;
    float s = 0.f;
#pragma unroll
    for (int i = 0; i < CC / 64; ++i) {
        int c = i * 64 + lane;
        float v = a[c] + bq[c] - S * cp[c];
        vo[c] = v;
        s = fmaf(v, v, s);
    }
#pragma unroll
    for (int off = 32; off > 0; off >>= 1) s += __shfl_xor(s, off);
    if (lane == 0) {
        float iv = 1.0f / fmaxf(sqrtf(s), EPS);
        rinv[r] = iv;
        rsq[r] = s * iv * iv;
    }
}

// ---------------- final scale (tinv computed in-block from rsq) ----------------
__global__ void k_final(const float* __restrict__ vlad, const float* __restrict__ rinv,
                        const float* __restrict__ rsq, float* __restrict__ out) {
    size_t i4 = (size_t)blockIdx.x * 256 + threadIdx.x;   // over 262144 float4s
    int row = (int)(i4 >> 7);
    int n = row >> 6;
    int lane = threadIdx.x & 63;
    float s = rsq[(n << 6) + lane];
#pragma unroll
    for (int off = 32; off > 0; off >>= 1) s += __shfl_xor(s, off);
    float tinv = 1.0f / fmaxf(sqrtf(s), EPS);
    float4 v = ((const float4*)vlad)[i4];
    float sc = rinv[row] * tinv;
    float4 o{v.x * sc, v.y * sc, v.z * sc, v.w * sc};
    ((float4*)out)[i4] = o;
}

extern "C" void kernel_launch(void* const* d_in, const int* in_sizes, int n_in,
                              void* d_out, int out_size, void* d_ws, size_t ws_size,
                              hipStream_t stream) {
    const float* x    = (const float*)d_in[0];
    const float* w    = (const float*)d_in[1];
    const float* bias = (const float*)d_in[2];
    const float* cent = (const float*)d_in[3];
    float* ws = (float*)d_ws;

    float* vlad  = ws;                                // 1048576
    float* vpart = vlad + (size_t)NN * KK * CC;       // 2097152 (two halves)
    float* Spart = vpart + (size_t)2 * NN * KK * CC;  // 16384 (8 partials)
    float* rinv  = Spart + 8 * NN * KK;               // 2048
    float* rsq   = rinv + NN * KK;                    // 2048
    unsigned int* sab = (unsigned int*)(rsq + NN * KK);   // 1048576 u32 (sa*iv bf16 pairs)

    float* out = (float*)d_out;

    k_logits<<<dim3(256), dim3(512), 0, stream>>>(x, w, bias, sab, Spart);
    k_vlad<<<dim3(512), dim3(512), 0, stream>>>(x, sab, vpart);
    k_rownorm<<<dim3(NN * KK / 4), dim3(256), 0, stream>>>(
        vpart, vpart + (size_t)NN * KK * CC, Spart, cent, vlad, rinv, rsq);
    k_final<<<dim3(1024), dim3(256), 0, stream>>>(vlad, rinv, rsq, out);
}

// Round 17
// 65.304 us; speedup vs baseline: 1.0835x; 1.0133x over previous
//
#include <hip/hip_runtime.h>
#include <math.h>

#define NN 32
#define CC 512
#define PP 1024   // H*W
#define KK 64
static constexpr float EPS = 1e-12f;

typedef __attribute__((ext_vector_type(8))) short bf16x8;
typedef __attribute__((ext_vector_type(4))) float f32x4;
typedef __attribute__((ext_vector_type(4))) unsigned int u32x4;
union FragU { u32x4 u; bf16x8 h; };

// pack two fp32 into one u32 of 2 bf16 (RNE)
__device__ __forceinline__ unsigned int bfpair(float lo, float hi) {
    unsigned int ul = __builtin_bit_cast(unsigned int, lo);
    unsigned int uh = __builtin_bit_cast(unsigned int, hi);
    ul = ul + 0x7FFFu + ((ul >> 16) & 1u);
    uh = uh + 0x7FFFu + ((uh >> 16) & 1u);
    return (ul >> 16) | (uh & 0xFFFF0000u);
}

// ---------------- fused pixnorm + logits(MFMA) + softmax -> sab=(sa*iv) bf16, Spart ----------------
// grid: 256 blocks = n(32) x 128-px tile(8). 512 threads = 8 waves.
// CHANGE vs R13: prefetch PFL issued AFTER the second barrier (drain overlaps MFMA).
__global__ void __launch_bounds__(512, 2) k_logits(
        const float* __restrict__ x, const float* __restrict__ w,
        const float* __restrict__ bias, unsigned int* __restrict__ sab,
        float* __restrict__ Spart) {
    int b = blockIdx.x;
    int n = b >> 3;
    int p0 = (b & 7) << 7;           // 128-px tile base
    int tid = threadIdx.x;
    int lane = tid & 63;
    int wv = __builtin_amdgcn_readfirstlane(tid >> 6);   // 0..7 = px tile
    int l15 = lane & 15, l4 = lane >> 4;
    int rp = tid >> 4;               // staging cpair row 0..31
    int px8 = (tid & 15) << 3;       // staging px octet

    __shared__ unsigned int smem_u[26240];   // 104960 B
    unsigned int* XP  = smem_u;              // 2 x [128][33] u32
    unsigned int* WBF = smem_u + 8448;       // [64][260] u32
    float* RED  = (float*)(smem_u + 25088);  // [8][128] ssq / S partials
    float* REDI = (float*)(smem_u + 26112);  // [128] inv per px

    // ---- stage whole W (fp32 -> bf16 pairs) into LDS once ----
    {
        int k = tid >> 3, cb = (tid & 7) << 5;   // cb in u32 pairs (32 pairs = 64 floats)
        const float* wsrc = w + (k << 9) + (cb << 1);
#pragma unroll
        for (int i = 0; i < 8; ++i) {
            float4 f0 = *(const float4*)&wsrc[(i << 3)];
            float4 f1 = *(const float4*)&wsrc[(i << 3) + 4];
            u32x4 v;
            v[0] = bfpair(f0.x, f0.y); v[1] = bfpair(f0.z, f0.w);
            v[2] = bfpair(f1.x, f1.y); v[3] = bfpair(f1.z, f1.w);
            *(u32x4*)&WBF[k * 260 + cb + (i << 2)] = v;
        }
    }

    const float* xb = x + (size_t)n * CC * PP + p0;

    f32x4 c0v = {0.f, 0.f, 0.f, 0.f};
    f32x4 c1v = {0.f, 0.f, 0.f, 0.f};
    f32x4 c2v = {0.f, 0.f, 0.f, 0.f};
    f32x4 c3v = {0.f, 0.f, 0.f, 0.f};
    float ssq[8] = {};
    float4 a0, a1, b0, b1;

#define PFL(i) { const float* xa = xb + (size_t)((i) * 64 + 2 * rp) * PP + px8; \
        a0 = *(const float4*)xa; a1 = *(const float4*)(xa + 4); \
        b0 = *(const float4*)(xa + PP); b1 = *(const float4*)(xa + PP + 4); }

#define MSTEP(H) { \
        FragU bfr; \
        int ob = xo + ((H) << 4); \
        bfr.u[0] = xq[ob]; bfr.u[1] = xq[ob + 1]; \
        bfr.u[2] = xq[ob + 2]; bfr.u[3] = xq[ob + 3]; \
        int oa = l15 * 260 + (i << 5) + ((H) << 4) + (l4 << 2); \
        FragU af; \
        af.u = *(const u32x4*)&WBF[oa]; \
        c0v = __builtin_amdgcn_mfma_f32_16x16x32_bf16(af.h, bfr.h, c0v, 0, 0, 0); \
        af.u = *(const u32x4*)&WBF[oa + 4160]; \
        c1v = __builtin_amdgcn_mfma_f32_16x16x32_bf16(af.h, bfr.h, c1v, 0, 0, 0); \
        af.u = *(const u32x4*)&WBF[oa + 8320]; \
        c2v = __builtin_amdgcn_mfma_f32_16x16x32_bf16(af.h, bfr.h, c2v, 0, 0, 0); \
        af.u = *(const u32x4*)&WBF[oa + 12480]; \
        c3v = __builtin_amdgcn_mfma_f32_16x16x32_bf16(af.h, bfr.h, c3v, 0, 0, 0); \
    }

    PFL(0);
#pragma unroll 1
    for (int i = 0; i < 8; ++i) {
        __syncthreads();   // buffer free + (i==0) WBF visible; drains last iter's PFL (overlapped)
        unsigned int* xp = XP + (i & 1) * 4224;
        float av[8] = {a0.x, a0.y, a0.z, a0.w, a1.x, a1.y, a1.z, a1.w};
        float bv[8] = {b0.x, b0.y, b0.z, b0.w, b1.x, b1.y, b1.z, b1.w};
#pragma unroll
        for (int j = 0; j < 8; ++j) {
            xp[(px8 + j) * 33 + rp] = bfpair(av[j], bv[j]);
            ssq[j] = fmaf(av[j], av[j], fmaf(bv[j], bv[j], ssq[j]));
        }
        __syncthreads();   // staged chunk visible (no vmem pending here)
        if (i < 7) { PFL(i + 1); }   // issue AFTER barrier: drain overlaps MFMA below
        const unsigned int* xq = XP + (i & 1) * 4224;
        int xo = (wv * 16 + l15) * 33 + (l4 << 2);
        MSTEP(0);
        MSTEP(1);
    }
#undef PFL
#undef MSTEP

    // ---- per-px ssq -> inv ----
#pragma unroll
    for (int j = 0; j < 8; ++j) {
        ssq[j] += __shfl_xor(ssq[j], 16);
        ssq[j] += __shfl_xor(ssq[j], 32);
    }
    if (l4 == 0) {
#pragma unroll
        for (int j = 0; j < 8; ++j) RED[(wv << 7) + px8 + j] = ssq[j];
    }
    __syncthreads();
    if (tid < 128) {
        float s = 0.f;
#pragma unroll
        for (int w8 = 0; w8 < 8; ++w8) s += RED[(w8 << 7) + tid];
        REDI[tid] = 1.0f / fmaxf(sqrtf(s), EPS);
    }
    __syncthreads();

    // ---- softmax over 64 k (in-lane 16 + shfl over l4) ----
    float inv = REDI[(wv << 4) + l15];
    float lg[16];
#pragma unroll
    for (int r = 0; r < 4; ++r) {
        lg[r]      = c0v[r];
        lg[4 + r]  = c1v[r];
        lg[8 + r]  = c2v[r];
        lg[12 + r] = c3v[r];
    }
    float m = -1e30f;
#pragma unroll
    for (int kk = 0; kk < 16; ++kk) {
        int k = ((kk >> 2) << 4) + (l4 << 2) + (kk & 3);
        lg[kk] = fmaf(lg[kk], inv, bias[k]);
        m = fmaxf(m, lg[kk]);
    }
    m = fmaxf(m, __shfl_xor(m, 16));
    m = fmaxf(m, __shfl_xor(m, 32));
    float sm = 0.f;
#pragma unroll
    for (int kk = 0; kk < 16; ++kk) {
        lg[kk] = __expf(lg[kk] - m);
        sm += lg[kk];
    }
    sm += __shfl_xor(sm, 16);
    sm += __shfl_xor(sm, 32);
    float si = 1.0f / sm;

    // ---- store sab = sa*iv (bf16 pairs) + S partials ----
    int pcol = p0 + (wv << 4) + l15;
#pragma unroll
    for (int kk = 0; kk < 16; ++kk) {
        int k = ((kk >> 2) << 4) + (l4 << 2) + (kk & 3);
        float v = lg[kk] * si;                 // sa
        float vs = v;
        vs += __shfl_xor(vs, 1);
        vs += __shfl_xor(vs, 2);
        vs += __shfl_xor(vs, 4);
        vs += __shfl_xor(vs, 8);               // sum over the wave's 16 px
        float vi = v * inv;                    // sa*iv
        float vh = __shfl_xor(vi, 1);
        if ((l15 & 1) == 0)
            sab[(((size_t)(n * KK + k) << 10) + pcol) >> 1] = bfpair(vi, vh);
        if (l15 == 0) RED[(wv << 6) + k] = vs;
    }
    __syncthreads();
    if (tid < 64) {
        float s = 0.f;
#pragma unroll
        for (int w8 = 0; w8 < 8; ++w8) s += RED[(w8 << 6) + tid];
        Spart[(((b & 7) * NN) + n) * KK + tid] = s;
    }
}

// ---------------- vpart[half][n][k][c] = sum_{p in half} (sa*iv)*x  (MFMA) ----------------
// grid: 512 blocks = n(32) x p-half(2) x 64-c tile(8). 512 threads = 8 waves.
// CHANGE vs R16: LOADNEXT issued AFTER the second barrier -> the compiler's
// vmcnt(0) drain (emitted before the NEXT chunk's first barrier) overlaps a
// full compute phase instead of stalling cold.
__global__ void __launch_bounds__(512, 2) k_vlad(
        const float* __restrict__ x, const unsigned int* __restrict__ sab,
        float* __restrict__ vpart) {
    int b = blockIdx.x;
    int nb = b >> 4;
    int half = (b >> 3) & 1;
    int c0 = (b & 7) << 6;
    int tid = threadIdx.x;
    int lane = tid & 63;
    int wv = __builtin_amdgcn_readfirstlane(tid >> 6);   // 0..7
    int l15 = lane & 15, l4 = lane >> 4;
    int kt = wv & 3;
    int ctb = (wv >> 2) << 1;      // 0 or 2

    __shared__ unsigned int smem_u[16896];   // 67584 B -> 2 blocks/CU
    unsigned int* SAB = smem_u;              // [2][64][66] sa*iv bf16 pairs
    unsigned int* XT  = smem_u + 8448;       // [2][64][66] x bf16 pairs

    int tr = tid >> 3;             // row 0..63 (k for sab, c for x)
    int tc = tid & 7;              // col group 0..7 (32 B each)

    const unsigned int* sap = sab + ((size_t)(nb * KK + tr) << 9) + (half << 8) + (tc << 3);
    const float* xbp = x + ((size_t)(nb * CC + c0 + tr) << 10) + (half << 9) + (tc << 4);

    f32x4 acc0 = {0.f, 0.f, 0.f, 0.f};
    f32x4 acc1 = {0.f, 0.f, 0.f, 0.f};

    u32x4 sA0, sA1, sB0, sB1;
    float4 xA0, xA1, xA2, xA3, xB0, xB1, xB2, xB3;

#define LOADA(i) { sA0 = *(const u32x4*)(sap + (i) * 64); \
        sA1 = *(const u32x4*)(sap + (i) * 64 + 4); \
        xA0 = *(const float4*)(xbp + (i) * 128); \
        xA1 = *(const float4*)(xbp + (i) * 128 + 4); \
        xA2 = *(const float4*)(xbp + (i) * 128 + 8); \
        xA3 = *(const float4*)(xbp + (i) * 128 + 12); }
#define LOADB(i) { sB0 = *(const u32x4*)(sap + (i) * 64); \
        sB1 = *(const u32x4*)(sap + (i) * 64 + 4); \
        xB0 = *(const float4*)(xbp + (i) * 128); \
        xB1 = *(const float4*)(xbp + (i) * 128 + 4); \
        xB2 = *(const float4*)(xbp + (i) * 128 + 8); \
        xB3 = *(const float4*)(xbp + (i) * 128 + 12); }

#define BODY(S0, S1, X0, X1, X2, X3, i, LOADNEXT) { \
        __syncthreads(); \
        int bo = ((i) & 1) * 4224; \
        unsigned int* sd = SAB + bo + tr * 66 + (tc << 3); \
        *(u32x4*)sd = S0; *(u32x4*)(sd + 4) = S1; \
        u32x4 xw0, xw1; \
        xw0[0] = bfpair(X0.x, X0.y); xw0[1] = bfpair(X0.z, X0.w); \
        xw0[2] = bfpair(X1.x, X1.y); xw0[3] = bfpair(X1.z, X1.w); \
        xw1[0] = bfpair(X2.x, X2.y); xw1[1] = bfpair(X2.z, X2.w); \
        xw1[2] = bfpair(X3.x, X3.y); xw1[3] = bfpair(X3.z, X3.w); \
        unsigned int* xd = XT + bo + tr * 66 + (tc << 3); \
        *(u32x4*)xd = xw0; *(u32x4*)(xd + 4) = xw1; \
        __syncthreads(); \
        LOADNEXT; /* issue after barrier: latency hides under MFMA below */ \
        const unsigned int* sa_l = SAB + bo + (kt * 16 + l15) * 66 + (l4 << 2); \
        const unsigned int* xb_l = XT + bo + (ctb * 16 + l15) * 66 + (l4 << 2); \
        _Pragma("unroll") \
        for (int ks = 0; ks < 4; ++ks) { \
            FragU af, bf0, bf1; \
            af.u  = *(const u32x4*)(sa_l + ks * 16); \
            bf0.u = *(const u32x4*)(xb_l + ks * 16); \
            bf1.u = *(const u32x4*)(xb_l + 16 * 66 + ks * 16); \
            acc0 = __builtin_amdgcn_mfma_f32_16x16x32_bf16(af.h, bf0.h, acc0, 0, 0, 0); \
            acc1 = __builtin_amdgcn_mfma_f32_16x16x32_bf16(af.h, bf1.h, acc1, 0, 0, 0); \
        } \
    }

    LOADA(0); LOADB(1);
    BODY(sA0, sA1, xA0, xA1, xA2, xA3, 0, LOADA(2));
    BODY(sB0, sB1, xB0, xB1, xB2, xB3, 1, LOADB(3));
    BODY(sA0, sA1, xA0, xA1, xA2, xA3, 2, );
    BODY(sB0, sB1, xB0, xB1, xB2, xB3, 3, );
#undef LOADA
#undef LOADB
#undef BODY

    // ---- epilogue: write raw partial accumulators ----
    float* vbase = vpart + (size_t)half * NN * KK * CC;
#pragma unroll
    for (int r = 0; r < 4; ++r) {
        int k = kt * 16 + (l4 << 2) + r;
        int cg = c0 + ctb * 16 + l15;
        float* vp = vbase + ((size_t)nb * KK + k) * CC + cg;
        vp[0]  = acc0[r];
        vp[16] = acc1[r];
    }
}

// ---------------- vlad = vp0+vp1-S*cent; per-row sumsq + inv norm ----------------
__global__ void k_rownorm(const float* __restrict__ vp0, const float* __restrict__ vp1,
                          const float* __restrict__ Spart, const float* __restrict__ cent,
                          float* __restrict__ vlad, float* __restrict__ rinv,
                          float* __restrict__ rsq) {
    int r = blockIdx.x * 4 + (threadIdx.x >> 6);   // n*KK+k
    int lane = threadIdx.x & 63;
    int n = r >> 6, k = r & 63;
    float S = 0.f;
#pragma unroll
    for (int pt = 0; pt < 8; ++pt) S += Spart[(pt * NN + n) * KK + k];
    const float* a  = vp0 + (size_t)r * CC;
    const float* bq = vp1 + (size_t)r * CC;
    const float* cp = cent + (size_t)k * CC;
    float* vo = vlad + (size_t)r * CC;
    float s = 0.f;
#pragma unroll
    for (int i = 0; i < CC / 64; ++i) {
        int c = i * 64 + lane;
        float v = a[c] + bq[c] - S * cp[c];
        vo[c] = v;
        s = fmaf(v, v, s);
    }
#pragma unroll
    for (int off = 32; off > 0; off >>= 1) s += __shfl_xor(s, off);
    if (lane == 0) {
        float iv = 1.0f / fmaxf(sqrtf(s), EPS);
        rinv[r] = iv;
        rsq[r] = s * iv * iv;
    }
}

// ---------------- final scale (tinv computed in-block from rsq) ----------------
__global__ void k_final(const float* __restrict__ vlad, const float* __restrict__ rinv,
                        const float* __restrict__ rsq, float* __restrict__ out) {
    size_t i4 = (size_t)blockIdx.x * 256 + threadIdx.x;   // over 262144 float4s
    int row = (int)(i4 >> 7);
    int n = row >> 6;
    int lane = threadIdx.x & 63;
    float s = rsq[(n << 6) + lane];
#pragma unroll
    for (int off = 32; off > 0; off >>= 1) s += __shfl_xor(s, off);
    float tinv = 1.0f / fmaxf(sqrtf(s), EPS);
    float4 v = ((const float4*)vlad)[i4];
    float sc = rinv[row] * tinv;
    float4 o{v.x * sc, v.y * sc, v.z * sc, v.w * sc};
    ((float4*)out)[i4] = o;
}

extern "C" void kernel_launch(void* const* d_in, const int* in_sizes, int n_in,
                              void* d_out, int out_size, void* d_ws, size_t ws_size,
                              hipStream_t stream) {
    const float* x    = (const float*)d_in[0];
    const float* w    = (const float*)d_in[1];
    const float* bias = (const float*)d_in[2];
    const float* cent = (const float*)d_in[3];
    float* ws = (float*)d_ws;

    float* vlad  = ws;                                // 1048576
    float* vpart = vlad + (size_t)NN * KK * CC;       // 2097152 (two halves)
    float* Spart = vpart + (size_t)2 * NN * KK * CC;  // 16384 (8 partials)
    float* rinv  = Spart + 8 * NN * KK;               // 2048
    float* rsq   = rinv + NN * KK;                    // 2048
    unsigned int* sab = (unsigned int*)(rsq + NN * KK);   // 1048576 u32 (sa*iv bf16 pairs)

    float* out = (float*)d_out;

    k_logits<<<dim3(256), dim3(512), 0, stream>>>(x, w, bias, sab, Spart);
    k_vlad<<<dim3(512), dim3(512), 0, stream>>>(x, sab, vpart);
    k_rownorm<<<dim3(NN * KK / 4), dim3(256), 0, stream>>>(
        vpart, vpart + (size_t)NN * KK * CC, Spart, cent, vlad, rinv, rsq);
    k_final<<<dim3(1024), dim3(256), 0, stream>>>(vlad, rinv, rsq, out);
}

// Round 18
// 63.855 us; speedup vs baseline: 1.1081x; 1.0227x over previous
//
#include <hip/hip_runtime.h>
#include <math.h>

#define NN 32
#define CC 512
#define PP 1024   // H*W
#define KK 64
static constexpr float EPS = 1e-12f;

typedef __attribute__((ext_vector_type(8))) short bf16x8;
typedef __attribute__((ext_vector_type(4))) float f32x4;
typedef __attribute__((ext_vector_type(4))) unsigned int u32x4;
union FragU { u32x4 u; bf16x8 h; };

// pack two fp32 into one u32 of 2 bf16 (RNE)
__device__ __forceinline__ unsigned int bfpair(float lo, float hi) {
    unsigned int ul = __builtin_bit_cast(unsigned int, lo);
    unsigned int uh = __builtin_bit_cast(unsigned int, hi);
    ul = ul + 0x7FFFu + ((ul >> 16) & 1u);
    uh = uh + 0x7FFFu + ((uh >> 16) & 1u);
    return (ul >> 16) | (uh & 0xFFFF0000u);
}

// ---------------- fused pixnorm + logits(MFMA) + softmax -> sab=(sa*iv) bf16, Spart ----------------
// grid: 256 blocks = n(32) x 128-px tile(8). 512 threads = 8 waves. (R17 verbatim)
__global__ void __launch_bounds__(512, 2) k_logits(
        const float* __restrict__ x, const float* __restrict__ w,
        const float* __restrict__ bias, unsigned int* __restrict__ sab,
        float* __restrict__ Spart) {
    int b = blockIdx.x;
    int n = b >> 3;
    int p0 = (b & 7) << 7;           // 128-px tile base
    int tid = threadIdx.x;
    int lane = tid & 63;
    int wv = __builtin_amdgcn_readfirstlane(tid >> 6);   // 0..7 = px tile
    int l15 = lane & 15, l4 = lane >> 4;
    int rp = tid >> 4;               // staging cpair row 0..31
    int px8 = (tid & 15) << 3;       // staging px octet

    __shared__ unsigned int smem_u[26240];   // 104960 B
    unsigned int* XP  = smem_u;              // 2 x [128][33] u32
    unsigned int* WBF = smem_u + 8448;       // [64][260] u32
    float* RED  = (float*)(smem_u + 25088);  // [8][128] ssq / S partials
    float* REDI = (float*)(smem_u + 26112);  // [128] inv per px

    // ---- stage whole W (fp32 -> bf16 pairs) into LDS once ----
    {
        int k = tid >> 3, cb = (tid & 7) << 5;   // cb in u32 pairs (32 pairs = 64 floats)
        const float* wsrc = w + (k << 9) + (cb << 1);
#pragma unroll
        for (int i = 0; i < 8; ++i) {
            float4 f0 = *(const float4*)&wsrc[(i << 3)];
            float4 f1 = *(const float4*)&wsrc[(i << 3) + 4];
            u32x4 v;
            v[0] = bfpair(f0.x, f0.y); v[1] = bfpair(f0.z, f0.w);
            v[2] = bfpair(f1.x, f1.y); v[3] = bfpair(f1.z, f1.w);
            *(u32x4*)&WBF[k * 260 + cb + (i << 2)] = v;
        }
    }

    const float* xb = x + (size_t)n * CC * PP + p0;

    f32x4 c0v = {0.f, 0.f, 0.f, 0.f};
    f32x4 c1v = {0.f, 0.f, 0.f, 0.f};
    f32x4 c2v = {0.f, 0.f, 0.f, 0.f};
    f32x4 c3v = {0.f, 0.f, 0.f, 0.f};
    float ssq[8] = {};
    float4 a0, a1, b0, b1;

#define PFL(i) { const float* xa = xb + (size_t)((i) * 64 + 2 * rp) * PP + px8; \
        a0 = *(const float4*)xa; a1 = *(const float4*)(xa + 4); \
        b0 = *(const float4*)(xa + PP); b1 = *(const float4*)(xa + PP + 4); }

#define MSTEP(H) { \
        FragU bfr; \
        int ob = xo + ((H) << 4); \
        bfr.u[0] = xq[ob]; bfr.u[1] = xq[ob + 1]; \
        bfr.u[2] = xq[ob + 2]; bfr.u[3] = xq[ob + 3]; \
        int oa = l15 * 260 + (i << 5) + ((H) << 4) + (l4 << 2); \
        FragU af; \
        af.u = *(const u32x4*)&WBF[oa]; \
        c0v = __builtin_amdgcn_mfma_f32_16x16x32_bf16(af.h, bfr.h, c0v, 0, 0, 0); \
        af.u = *(const u32x4*)&WBF[oa + 4160]; \
        c1v = __builtin_amdgcn_mfma_f32_16x16x32_bf16(af.h, bfr.h, c1v, 0, 0, 0); \
        af.u = *(const u32x4*)&WBF[oa + 8320]; \
        c2v = __builtin_amdgcn_mfma_f32_16x16x32_bf16(af.h, bfr.h, c2v, 0, 0, 0); \
        af.u = *(const u32x4*)&WBF[oa + 12480]; \
        c3v = __builtin_amdgcn_mfma_f32_16x16x32_bf16(af.h, bfr.h, c3v, 0, 0, 0); \
    }

    PFL(0);
#pragma unroll 1
    for (int i = 0; i < 8; ++i) {
        __syncthreads();   // buffer free + (i==0) WBF visible; drains last iter's PFL (overlapped)
        unsigned int* xp = XP + (i & 1) * 4224;
        float av[8] = {a0.x, a0.y, a0.z, a0.w, a1.x, a1.y, a1.z, a1.w};
        float bv[8] = {b0.x, b0.y, b0.z, b0.w, b1.x, b1.y, b1.z, b1.w};
#pragma unroll
        for (int j = 0; j < 8; ++j) {
            xp[(px8 + j) * 33 + rp] = bfpair(av[j], bv[j]);
            ssq[j] = fmaf(av[j], av[j], fmaf(bv[j], bv[j], ssq[j]));
        }
        __syncthreads();   // staged chunk visible (no vmem pending here)
        if (i < 7) { PFL(i + 1); }   // issue AFTER barrier: drain overlaps MFMA below
        const unsigned int* xq = XP + (i & 1) * 4224;
        int xo = (wv * 16 + l15) * 33 + (l4 << 2);
        MSTEP(0);
        MSTEP(1);
    }
#undef PFL
#undef MSTEP

    // ---- per-px ssq -> inv ----
#pragma unroll
    for (int j = 0; j < 8; ++j) {
        ssq[j] += __shfl_xor(ssq[j], 16);
        ssq[j] += __shfl_xor(ssq[j], 32);
    }
    if (l4 == 0) {
#pragma unroll
        for (int j = 0; j < 8; ++j) RED[(wv << 7) + px8 + j] = ssq[j];
    }
    __syncthreads();
    if (tid < 128) {
        float s = 0.f;
#pragma unroll
        for (int w8 = 0; w8 < 8; ++w8) s += RED[(w8 << 7) + tid];
        REDI[tid] = 1.0f / fmaxf(sqrtf(s), EPS);
    }
    __syncthreads();

    // ---- softmax over 64 k (in-lane 16 + shfl over l4) ----
    float inv = REDI[(wv << 4) + l15];
    float lg[16];
#pragma unroll
    for (int r = 0; r < 4; ++r) {
        lg[r]      = c0v[r];
        lg[4 + r]  = c1v[r];
        lg[8 + r]  = c2v[r];
        lg[12 + r] = c3v[r];
    }
    float m = -1e30f;
#pragma unroll
    for (int kk = 0; kk < 16; ++kk) {
        int k = ((kk >> 2) << 4) + (l4 << 2) + (kk & 3);
        lg[kk] = fmaf(lg[kk], inv, bias[k]);
        m = fmaxf(m, lg[kk]);
    }
    m = fmaxf(m, __shfl_xor(m, 16));
    m = fmaxf(m, __shfl_xor(m, 32));
    float sm = 0.f;
#pragma unroll
    for (int kk = 0; kk < 16; ++kk) {
        lg[kk] = __expf(lg[kk] - m);
        sm += lg[kk];
    }
    sm += __shfl_xor(sm, 16);
    sm += __shfl_xor(sm, 32);
    float si = 1.0f / sm;

    // ---- store sab = sa*iv (bf16 pairs) + S partials ----
    int pcol = p0 + (wv << 4) + l15;
#pragma unroll
    for (int kk = 0; kk < 16; ++kk) {
        int k = ((kk >> 2) << 4) + (l4 << 2) + (kk & 3);
        float v = lg[kk] * si;                 // sa
        float vs = v;
        vs += __shfl_xor(vs, 1);
        vs += __shfl_xor(vs, 2);
        vs += __shfl_xor(vs, 4);
        vs += __shfl_xor(vs, 8);               // sum over the wave's 16 px
        float vi = v * inv;                    // sa*iv
        float vh = __shfl_xor(vi, 1);
        if ((l15 & 1) == 0)
            sab[(((size_t)(n * KK + k) << 10) + pcol) >> 1] = bfpair(vi, vh);
        if (l15 == 0) RED[(wv << 6) + k] = vs;
    }
    __syncthreads();
    if (tid < 64) {
        float s = 0.f;
#pragma unroll
        for (int w8 = 0; w8 < 8; ++w8) s += RED[(w8 << 6) + tid];
        Spart[(((b & 7) * NN) + n) * KK + tid] = s;
    }
}

// ---------------- vlad[n][k][c] = sum_p (sa*iv)*x - S*cent  (MFMA, fused epilogue) ----------------
// grid: 256 blocks = n(32) x 64-c tile(8). 512 threads = 8 waves. Full P per block
// (16 chunks of 64 px). Epilogue: -S*cent folded in, final vlad written directly,
// per-block row-sumsq partials ssqpart[ct][n][k] via shfl+LDS reduce. k_rownorm deleted.
__global__ void __launch_bounds__(512, 2) k_vlad(
        const float* __restrict__ x, const unsigned int* __restrict__ sab,
        const float* __restrict__ Spart, const float* __restrict__ cent,
        float* __restrict__ vlad, float* __restrict__ ssqpart) {
    int b = blockIdx.x;
    int nb = b >> 3;
    int ct = b & 7;
    int c0 = ct << 6;
    int tid = threadIdx.x;
    int lane = tid & 63;
    int wv = __builtin_amdgcn_readfirstlane(tid >> 6);   // 0..7
    int l15 = lane & 15, l4 = lane >> 4;
    int kt = wv & 3;
    int ctb = (wv >> 2) << 1;      // 0 or 2

    __shared__ unsigned int smem_u[8576];   // 34304 B
    unsigned int* SAB = smem_u;             // [2][64][33] sa*iv bf16 pairs
    unsigned int* XT  = smem_u + 4224;      // [2][64][33] x bf16 pairs
    float* R2 = (float*)(smem_u + 8448);    // [8][16] row-sumsq partials

    int tr = tid >> 3;             // row 0..63 (k for sab, c for x)
    int tc = tid & 7;              // col group 0..7

    const unsigned int* sap = sab + ((size_t)(nb * KK + tr) << 9) + (tc << 2);
    const float* xbp = x + ((size_t)(nb * CC + c0 + tr) << 10) + (tc << 3);

    f32x4 acc0 = {0.f, 0.f, 0.f, 0.f};
    f32x4 acc1 = {0.f, 0.f, 0.f, 0.f};

    u32x4 sregA, sregB;
    float4 xrA0, xrA1, xrB0, xrB1;

#define LOADA(i) { sregA = *(const u32x4*)(sap + (i) * 32); \
        xrA0 = *(const float4*)(xbp + (i) * 64); \
        xrA1 = *(const float4*)(xbp + (i) * 64 + 4); }
#define LOADB(i) { sregB = *(const u32x4*)(sap + (i) * 32); \
        xrB0 = *(const float4*)(xbp + (i) * 64); \
        xrB1 = *(const float4*)(xbp + (i) * 64 + 4); }

#define BODY(SREG, XR0, XR1, i, LOADNEXT) { \
        __syncthreads(); \
        int bo = ((i) & 1) * 2112; \
        *(u32x4*)(SAB + bo + tr * 33 + (tc << 2)) = SREG; \
        u32x4 xw; \
        xw[0] = bfpair(XR0.x, XR0.y); \
        xw[1] = bfpair(XR0.z, XR0.w); \
        xw[2] = bfpair(XR1.x, XR1.y); \
        xw[3] = bfpair(XR1.z, XR1.w); \
        *(u32x4*)(XT + bo + tr * 33 + (tc << 2)) = xw; \
        __syncthreads(); \
        LOADNEXT; /* issue after barrier: latency hides under MFMA below */ \
        const unsigned int* sa_l = SAB + bo + (kt * 16 + l15) * 33 + (l4 << 2); \
        const unsigned int* xb0  = XT + bo + (ctb * 16 + l15) * 33 + (l4 << 2); \
        _Pragma("unroll") \
        for (int s = 0; s < 2; ++s) { \
            FragU af, bf0, bf1; \
            af.u  = *(const u32x4*)(sa_l + s * 16); \
            bf0.u = *(const u32x4*)(xb0 + s * 16); \
            bf1.u = *(const u32x4*)(xb0 + 16 * 33 + s * 16); \
            acc0 = __builtin_amdgcn_mfma_f32_16x16x32_bf16(af.h, bf0.h, acc0, 0, 0, 0); \
            acc1 = __builtin_amdgcn_mfma_f32_16x16x32_bf16(af.h, bf1.h, acc1, 0, 0, 0); \
        } \
    }

    LOADA(0); LOADB(1);
#pragma unroll 1
    for (int i = 0; i < 16; i += 2) {
        if (i < 14) { BODY(sregA, xrA0, xrA1, i, LOADA(i + 2)); }
        else        { BODY(sregA, xrA0, xrA1, i, ); }
        if (i < 13) { BODY(sregB, xrB0, xrB1, i + 1, LOADB(i + 3)); }
        else        { BODY(sregB, xrB0, xrB1, i + 1, ); }
    }
#undef LOADA
#undef LOADB
#undef BODY

    // ---- fused epilogue: vlad = acc - S*cent, plus row-sumsq partials ----
#pragma unroll
    for (int r = 0; r < 4; ++r) {
        int k = kt * 16 + (l4 << 2) + r;
        float S = 0.f;
#pragma unroll
        for (int pt = 0; pt < 8; ++pt) S += Spart[(pt * NN + nb) * KK + k];
        int cg = c0 + ctb * 16 + l15;
        const float* cp = cent + (size_t)k * CC + cg;
        float v0 = fmaf(-S, cp[0],  acc0[r]);
        float v1 = fmaf(-S, cp[16], acc1[r]);
        float* vp = vlad + ((size_t)nb * KK + k) * CC + cg;
        vp[0]  = v0;
        vp[16] = v1;
        float sq = fmaf(v0, v0, v1 * v1);
        sq += __shfl_xor(sq, 1);
        sq += __shfl_xor(sq, 2);
        sq += __shfl_xor(sq, 4);
        sq += __shfl_xor(sq, 8);               // reduce over l15 (16 lanes)
        if (l15 == 0) R2[(wv << 4) + (l4 << 2) + r] = sq;
    }
    __syncthreads();
    if (tid < 64) {
        int kt2 = tid >> 4, kl = tid & 15;
        ssqpart[(ct * NN + nb) * KK + tid] =
            R2[(kt2 << 4) + kl] + R2[((kt2 + 4) << 4) + kl];
    }
}

// ---------------- final scale: rinv/tinv from ssqpart, out = vlad*rinv*tinv ----------------
// grid: 1024 blocks x 256 thr over 262144 float4s. One row per wave.
__global__ void k_final(const float* __restrict__ vlad, const float* __restrict__ ssqpart,
                        float* __restrict__ out) {
    size_t i4 = (size_t)blockIdx.x * 256 + threadIdx.x;
    int row = (int)(i4 >> 7);
    int n = row >> 6;
    int lane = threadIdx.x & 63;
    // per-lane: raw row sumsq for k=lane of this n (sum the 8 c-tile partials)
    float s = 0.f;
#pragma unroll
    for (int ctile = 0; ctile < 8; ++ctile)
        s += ssqpart[(ctile * NN + n) * KK + lane];
    float iv = 1.0f / fmaxf(sqrtf(s), EPS);
    float rq = s * iv * iv;
#pragma unroll
    for (int off = 32; off > 0; off >>= 1) rq += __shfl_xor(rq, off);
    float tinv = 1.0f / fmaxf(sqrtf(rq), EPS);
    float rinv = __shfl(iv, row & 63);   // own row's inverse norm
    float4 v = ((const float4*)vlad)[i4];
    float sc = rinv * tinv;
    float4 o{v.x * sc, v.y * sc, v.z * sc, v.w * sc};
    ((float4*)out)[i4] = o;
}

extern "C" void kernel_launch(void* const* d_in, const int* in_sizes, int n_in,
                              void* d_out, int out_size, void* d_ws, size_t ws_size,
                              hipStream_t stream) {
    const float* x    = (const float*)d_in[0];
    const float* w    = (const float*)d_in[1];
    const float* bias = (const float*)d_in[2];
    const float* cent = (const float*)d_in[3];
    float* ws = (float*)d_ws;

    float* vlad    = ws;                              // 1048576
    float* Spart   = vlad + (size_t)NN * KK * CC;     // 16384 (8 px-tile partials)
    float* ssqpart = Spart + 8 * NN * KK;             // 16384 (8 c-tile partials)
    unsigned int* sab = (unsigned int*)(ssqpart + 8 * NN * KK);   // 1048576 u32

    float* out = (float*)d_out;

    k_logits<<<dim3(256), dim3(512), 0, stream>>>(x, w, bias, sab, Spart);
    k_vlad<<<dim3(256), dim3(512), 0, stream>>>(x, sab, Spart, cent, vlad, ssqpart);
    k_final<<<dim3(1024), dim3(256), 0, stream>>>(vlad, ssqpart, out);
}